// Round 1
// baseline (826.516 us; speedup 1.0000x reference)
//
#include <hip/hip_runtime.h>
#include <cstdint>
#include <type_traits>

typedef uint16_t u16;
typedef uint32_t u32;
typedef __attribute__((ext_vector_type(4))) float f32x4;
typedef __attribute__((ext_vector_type(8))) __bf16 vbf8;
typedef __attribute__((ext_vector_type(8))) short vs8;

// ---- MFMA operand-type hedge: prefer v8bf16, fall back to v8i16 ----
template <typename T, typename = void>
struct CanMfma : std::false_type {};
template <typename T>
struct CanMfma<T, std::void_t<decltype(__builtin_amdgcn_mfma_f32_16x16x32_bf16(
    std::declval<T>(), std::declval<T>(), std::declval<f32x4>(), 0, 0, 0))>>
    : std::true_type {};
typedef std::conditional_t<CanMfma<vbf8>::value, vbf8, vs8> frag_t;

__device__ __forceinline__ f32x4 mfma_bf16(frag_t a, frag_t b, f32x4 c) {
  return __builtin_amdgcn_mfma_f32_16x16x32_bf16(a, b, c, 0, 0, 0);
}

__device__ __forceinline__ u16 f2bf(float f) {
  u32 u = __builtin_bit_cast(u32, f);
  u32 r = (u + 0x7FFFu + ((u >> 16) & 1u)) >> 16;
  return (u16)r;
}

__device__ __forceinline__ void gload_lds16(const void* g, void* l) {
  __builtin_amdgcn_global_load_lds(
      (const __attribute__((address_space(1))) void*)g,
      (__attribute__((address_space(3))) void*)l, 16, 0, 0);
}

// ---------------- cast fp32 -> bf16 (vectorized, 8 elems/thread/iter) ----------------
__global__ __launch_bounds__(256) void cast_f32_bf16(
    const float* __restrict__ in, u16* __restrict__ out, int n8) {
  int i = blockIdx.x * 256 + threadIdx.x;
  const int stride = gridDim.x * 256;
  for (; i < n8; i += stride) {
    const float4 a  = ((const float4*)in)[(size_t)i * 2];
    const float4 b2 = ((const float4*)in)[(size_t)i * 2 + 1];
    uint4 o;
    o.x = (u32)f2bf(a.x)  | ((u32)f2bf(a.y)  << 16);
    o.y = (u32)f2bf(a.z)  | ((u32)f2bf(a.w)  << 16);
    o.z = (u32)f2bf(b2.x) | ((u32)f2bf(b2.y) << 16);
    o.w = (u32)f2bf(b2.z) | ((u32)f2bf(b2.w) << 16);
    ((uint4*)out)[(size_t)i] = o;
  }
}

// ---------------- transpose + cast: in[K][N] f32 -> out[N][K] bf16 ----------------
__global__ __launch_bounds__(256) void transpose_cast(
    const float* __restrict__ in, u16* __restrict__ out, int K, int N) {
  __shared__ float tile[32][33];
  const int k0 = blockIdx.x * 32, n0 = blockIdx.y * 32;
  const int tr = threadIdx.x >> 5, tc = threadIdx.x & 31;
#pragma unroll
  for (int i = 0; i < 4; ++i)
    tile[tr + i * 8][tc] = in[(size_t)(k0 + tr + i * 8) * N + (n0 + tc)];
  __syncthreads();
#pragma unroll
  for (int i = 0; i < 4; ++i)
    out[(size_t)(n0 + tr + i * 8) * K + (k0 + tc)] = f2bf(tile[tc][tr + i * 8]);
}

// ---------------- GEMM: C[M][N] = A[M][K](bf16) @ Bt[N][K](bf16)^T + bias ----------------
// m97 structure: 128x128 tile, BK=32, 4 waves (2x2), global_load_lds w16, 2 barriers/K-step.
template <bool OUT_BF16>
__global__ __launch_bounds__(256) void gemm_bt(
    const u16* __restrict__ A, const u16* __restrict__ Bt,
    const float* __restrict__ bias, void* __restrict__ Cout,
    int M, int N, int K, int Mtiles, int Ntiles) {
  __shared__ char Al[128 * 32 * 2];
  __shared__ char Bl[128 * 32 * 2];

  const int nwg = Mtiles * Ntiles;           // must be divisible by 8
  int bid = (int)blockIdx.x;
  bid = (bid & 7) * (nwg >> 3) + (bid >> 3); // XCD-aware swizzle (bijective)
  const int mt = bid / Ntiles, nt = bid % Ntiles;
  const int m0 = mt * 128, n0 = nt * 128;

  const int tid = (int)threadIdx.x;
  const int lane = tid & 63;
  const int wv = tid >> 6;
  const int wm = wv & 1, wn = wv >> 1;
  const int lr = lane & 15, lg = lane >> 4;
  const int rsub = lane >> 2;  // row-within-chunk
  const int slot = lane & 3;   // 16B slot within 64B row

  f32x4 zero4 = {0.f, 0.f, 0.f, 0.f};
  f32x4 acc[4][4];
#pragma unroll
  for (int i = 0; i < 4; ++i)
#pragma unroll
    for (int j = 0; j < 4; ++j) acc[i][j] = zero4;

  const int nk = K >> 5;
  for (int t = 0; t < nk; ++t) {
    __syncthreads();  // previous tile fully consumed
    const int k0 = t << 5;
#pragma unroll
    for (int c = 0; c < 2; ++c) {
      const int ci = c * 4 + wv;  // chunk 0..7, wave-uniform
      int ra = m0 + ci * 16 + rsub;
      if (ra >= M) ra = M - 1;  // clamp (harmless dup compute; stores guarded)
      gload_lds16(A + (size_t)ra * K + k0 + slot * 8, Al + ci * 1024);
      const int rb = n0 + ci * 16 + rsub;  // N is exact multiple of 128
      gload_lds16(Bt + (size_t)rb * K + k0 + slot * 8, Bl + ci * 1024);
    }
    __syncthreads();  // drains vmcnt(0): LDS tiles ready
    frag_t af[4], bf[4];
#pragma unroll
    for (int i = 0; i < 4; ++i) {
      af[i] = *(const frag_t*)(Al + (wm * 64 + i * 16 + lr) * 64 + lg * 16);
      bf[i] = *(const frag_t*)(Bl + (wn * 64 + i * 16 + lr) * 64 + lg * 16);
    }
#pragma unroll
    for (int i = 0; i < 4; ++i)
#pragma unroll
      for (int j = 0; j < 4; ++j)
        acc[i][j] = mfma_bf16(af[i], bf[j], acc[i][j]);
  }

  // epilogue: C row = (lg*4+reg), col = lr within each 16x16 frag (verified C/D layout)
#pragma unroll
  for (int j = 0; j < 4; ++j) {
    const int col = n0 + wn * 64 + j * 16 + lr;
    const float bv = bias[col];
#pragma unroll
    for (int i = 0; i < 4; ++i) {
      const int rbase = m0 + wm * 64 + i * 16 + lg * 4;
#pragma unroll
      for (int r = 0; r < 4; ++r) {
        const int row = rbase + r;
        if (row < M) {
          const float val = acc[i][j][r] + bv;
          if constexpr (OUT_BF16)
            ((u16*)Cout)[(size_t)row * N + col] = f2bf(val);
          else
            ((float*)Cout)[(size_t)row * N + col] = val;
        }
      }
    }
  }
}

// ---------------- attention: per (b, h, 64 q-rows) block, 4 waves x 16 q-rows ----------------
// Swapped QK^T: S^T tiles = mfma(K_frag, Q_frag) so softmax rows are 4-lane-local.
__global__ __launch_bounds__(256) void attn_kernel(
    const u16* __restrict__ Q, const u16* __restrict__ K,
    const u16* __restrict__ V, u16* __restrict__ O) {
  __shared__ u16 Kl[96][72];   // keys padded to 96, +8 pad vs bank conflicts
  __shared__ u16 Ql[64][72];
  __shared__ u16 Vt[64][104];  // V transposed: [dim][key], padded

  const int bid = blockIdx.x;
  const int qt = bid & 63;
  const int h = (bid >> 6) & 15;
  const int b = bid >> 10;
  const int tid = threadIdx.x;

  // stage K (zero-pad keys >= 77)
#pragma unroll
  for (int it = 0; it < 3; ++it) {
    const int idx = tid + it * 256;  // 96*8 slots of 16B
    const int key = idx >> 3, s = idx & 7;
    uint4 val{0u, 0u, 0u, 0u};
    if (key < 77)
      val = *(const uint4*)(K + ((size_t)(b * 77 + key)) * 1024 + h * 64 + s * 8);
    *(uint4*)(&Kl[key][s * 8]) = val;
  }
  // stage Q
#pragma unroll
  for (int it = 0; it < 2; ++it) {
    const int idx = tid + it * 256;
    const int qr = idx >> 3, s = idx & 7;
    *(uint4*)(&Ql[qr][s * 8]) =
        *(const uint4*)(Q + ((size_t)(b * 4096 + qt * 64 + qr)) * 1024 + h * 64 + s * 8);
  }
  // stage V transposed (zero-pad)
#pragma unroll
  for (int it = 0; it < 24; ++it) {
    const int idx = tid + it * 256;  // 96*64
    const int key = idx >> 6, d = idx & 63;
    u16 val = 0;
    if (key < 77) val = V[((size_t)(b * 77 + key)) * 1024 + h * 64 + d];
    Vt[d][key] = val;
  }
  __syncthreads();

  const int lane = tid & 63;
  const int wv = tid >> 6;  // wave -> q rows [wv*16, wv*16+16)
  const int lr = lane & 15;
  const int lg = lane >> 4;

  // S^T: 5 key-tiles x (K=64 -> 2 mfma)
  f32x4 zero4 = {0.f, 0.f, 0.f, 0.f};
  f32x4 sa[5] = {zero4, zero4, zero4, zero4, zero4};
#pragma unroll
  for (int ks = 0; ks < 2; ++ks) {
    frag_t qf = *(const frag_t*)(&Ql[wv * 16 + lr][ks * 32 + lg * 8]);
#pragma unroll
    for (int kt = 0; kt < 5; ++kt) {
      frag_t kf = *(const frag_t*)(&Kl[kt * 16 + lr][ks * 32 + lg * 8]);
      sa[kt] = mfma_bf16(kf, qf, sa[kt]);
    }
  }

  // softmax: lane owns q-row lr; its 20 keys are kt*16 + lg*4 + r; reduce over lanes ^16,^32
  float p[5][4];
  float mx = -3.0e38f;
#pragma unroll
  for (int kt = 0; kt < 5; ++kt)
#pragma unroll
    for (int r = 0; r < 4; ++r) {
      const int key = kt * 16 + lg * 4 + r;
      float s = sa[kt][r] * 0.125f;  // 1/sqrt(64)
      if (key >= 77) s = -3.0e38f;
      p[kt][r] = s;
      mx = fmaxf(mx, s);
    }
  mx = fmaxf(mx, __shfl_xor(mx, 16));
  mx = fmaxf(mx, __shfl_xor(mx, 32));
  float sum = 0.f;
#pragma unroll
  for (int kt = 0; kt < 5; ++kt)
#pragma unroll
    for (int r = 0; r < 4; ++r) {
      const float e = __expf(p[kt][r] - mx);
      p[kt][r] = e;
      sum += e;
    }
  sum += __shfl_xor(sum, 16);
  sum += __shfl_xor(sum, 32);
  const float rden = 1.0f / sum;
#pragma unroll
  for (int kt = 0; kt < 5; ++kt)
#pragma unroll
    for (int r = 0; r < 4; ++r) p[kt][r] *= rden;

  // pack P fragments: A-operand rows are lane-local (row = lr = q-row). kappa(l,j) =
  // (2kb + j>>2)*16 + lg*4 + (j&3); V B-fragment uses the identical kappa -> consistent.
  union FP { frag_t v; u16 e[8]; };
  frag_t pa[3];
#pragma unroll
  for (int kb = 0; kb < 3; ++kb) {
    FP f;
#pragma unroll
    for (int j = 0; j < 8; ++j) {
      const int kt = 2 * kb + (j >> 2);
      f.e[j] = (kt < 5) ? f2bf(p[kt][j & 3]) : (u16)0;
    }
    pa[kb] = f.v;
  }

  // O = P @ V : 4 dim-tiles x 3 K-blocks (96 keys)
  f32x4 oa[4] = {zero4, zero4, zero4, zero4};
#pragma unroll
  for (int nt = 0; nt < 4; ++nt) {
    const int d = nt * 16 + lr;
#pragma unroll
    for (int kb = 0; kb < 3; ++kb) {
      const int key0 = kb * 32 + lg * 4;
      FP vb;
      *(uint2*)(&vb.e[0]) = *(const uint2*)(&Vt[d][key0]);
      *(uint2*)(&vb.e[4]) = *(const uint2*)(&Vt[d][key0 + 16]);
      oa[nt] = mfma_bf16(pa[kb], vb.v, oa[nt]);
    }
  }

  // store: C layout row=(lg*4+r)=q-row, col=lr=dim
#pragma unroll
  for (int nt = 0; nt < 4; ++nt)
#pragma unroll
    for (int r = 0; r < 4; ++r) {
      const int qr = wv * 16 + lg * 4 + r;
      O[((size_t)(b * 4096 + qt * 64 + qr)) * 1024 + h * 64 + nt * 16 + lr] =
          f2bf(oa[nt][r]);
    }
}

// ---------------- launch ----------------
extern "C" void kernel_launch(void* const* d_in, const int* in_sizes, int n_in,
                              void* d_out, int out_size, void* d_ws, size_t ws_size,
                              hipStream_t stream) {
  const float* x  = (const float*)d_in[0];
  const float* p  = (const float*)d_in[1];
  const float* Wq = (const float*)d_in[2];
  const float* bq = (const float*)d_in[3];
  const float* Wk = (const float*)d_in[4];
  const float* bk = (const float*)d_in[5];
  const float* Wv = (const float*)d_in[6];
  const float* bv = (const float*)d_in[7];
  const float* Ww = (const float*)d_in[8];
  const float* bw = (const float*)d_in[9];

  char* ws = (char*)d_ws;
  if (ws_size < 281034752ULL) return;  // loud failure if scratch too small

  u16* x_bf = (u16*)(ws + 0);          // 65536x1024 bf16; reused as attn_out after GEMM1
  u16* q_bf = (u16*)(ws + 134217728);  // 65536x1024
  u16* wq_t = (u16*)(ws + 268435456);  // [1024][1024]
  u16* ww_t = (u16*)(ws + 270532608);  // [1024][1024]
  u16* wk_t = (u16*)(ws + 272629760);  // [1024][512]
  u16* wv_t = (u16*)(ws + 273678336);  // [1024][512]
  u16* p_bf = (u16*)(ws + 274726912);  // 1232x512
  u16* k_bf = (u16*)(ws + 275988480);  // 1232x1024
  u16* v_bf = (u16*)(ws + 278511616);  // 1232x1024

  cast_f32_bf16<<<4096, 256, 0, stream>>>(x, x_bf, 8388608);   // 67.1M elems
  cast_f32_bf16<<<308, 256, 0, stream>>>(p, p_bf, 78848);      // 630784 elems
  transpose_cast<<<dim3(32, 32), 256, 0, stream>>>(Wq, wq_t, 1024, 1024);
  transpose_cast<<<dim3(32, 32), 256, 0, stream>>>(Ww, ww_t, 1024, 1024);
  transpose_cast<<<dim3(16, 32), 256, 0, stream>>>(Wk, wk_t, 512, 1024);
  transpose_cast<<<dim3(16, 32), 256, 0, stream>>>(Wv, wv_t, 512, 1024);

  // K/V projections: M=1232 (pad to 10 tiles), K=512, N=1024
  gemm_bt<true><<<80, 256, 0, stream>>>(p_bf, wk_t, bk, k_bf, 1232, 1024, 512, 10, 8);
  gemm_bt<true><<<80, 256, 0, stream>>>(p_bf, wv_t, bv, v_bf, 1232, 1024, 512, 10, 8);
  // Q projection: 65536x1024x1024
  gemm_bt<true><<<4096, 256, 0, stream>>>(x_bf, wq_t, bq, q_bf, 65536, 1024, 1024, 512, 8);
  // attention (writes attn_out into x_bf region — x is dead after GEMM1)
  attn_kernel<<<16384, 256, 0, stream>>>(q_bf, k_bf, v_bf, x_bf);
  // out projection -> fp32
  gemm_bt<false><<<4096, 256, 0, stream>>>(x_bf, ww_t, bw, d_out, 65536, 1024, 1024, 512, 8);
}

// Round 2
// 711.393 us; speedup vs baseline: 1.1618x; 1.1618x over previous
//
#include <hip/hip_runtime.h>
#include <cstdint>
#include <type_traits>

typedef uint16_t u16;
typedef uint32_t u32;
typedef __attribute__((ext_vector_type(4))) float f32x4;
typedef __attribute__((ext_vector_type(8))) __bf16 vbf8;
typedef __attribute__((ext_vector_type(8))) short vs8;

// ---- MFMA operand-type hedge: prefer v8bf16, fall back to v8i16 ----
template <typename T, typename = void>
struct CanMfma : std::false_type {};
template <typename T>
struct CanMfma<T, std::void_t<decltype(__builtin_amdgcn_mfma_f32_16x16x32_bf16(
    std::declval<T>(), std::declval<T>(), std::declval<f32x4>(), 0, 0, 0))>>
    : std::true_type {};
typedef std::conditional_t<CanMfma<vbf8>::value, vbf8, vs8> frag_t;

__device__ __forceinline__ f32x4 mfma_bf16(frag_t a, frag_t b, f32x4 c) {
  return __builtin_amdgcn_mfma_f32_16x16x32_bf16(a, b, c, 0, 0, 0);
}

__device__ __forceinline__ u16 f2bf(float f) {
  u32 u = __builtin_bit_cast(u32, f);
  u32 r = (u + 0x7FFFu + ((u >> 16) & 1u)) >> 16;
  return (u16)r;
}

__device__ __forceinline__ void gload_lds16(const void* g, void* l) {
  __builtin_amdgcn_global_load_lds(
      (const __attribute__((address_space(1))) void*)g,
      (__attribute__((address_space(3))) void*)l, 16, 0, 0);
}

// ---------------- cast fp32 -> bf16 (vectorized, 8 elems/thread/iter) ----------------
__global__ __launch_bounds__(256) void cast_f32_bf16(
    const float* __restrict__ in, u16* __restrict__ out, int n8) {
  int i = blockIdx.x * 256 + threadIdx.x;
  const int stride = gridDim.x * 256;
  for (; i < n8; i += stride) {
    const float4 a  = ((const float4*)in)[(size_t)i * 2];
    const float4 b2 = ((const float4*)in)[(size_t)i * 2 + 1];
    uint4 o;
    o.x = (u32)f2bf(a.x)  | ((u32)f2bf(a.y)  << 16);
    o.y = (u32)f2bf(a.z)  | ((u32)f2bf(a.w)  << 16);
    o.z = (u32)f2bf(b2.x) | ((u32)f2bf(b2.y) << 16);
    o.w = (u32)f2bf(b2.z) | ((u32)f2bf(b2.w) << 16);
    ((uint4*)out)[(size_t)i] = o;
  }
}

// ---------------- transpose + cast: in[K][N] f32 -> out[N][K] bf16 ----------------
__global__ __launch_bounds__(256) void transpose_cast(
    const float* __restrict__ in, u16* __restrict__ out, int K, int N) {
  __shared__ float tile[32][33];
  const int k0 = blockIdx.x * 32, n0 = blockIdx.y * 32;
  const int tr = threadIdx.x >> 5, tc = threadIdx.x & 31;
#pragma unroll
  for (int i = 0; i < 4; ++i)
    tile[tr + i * 8][tc] = in[(size_t)(k0 + tr + i * 8) * N + (n0 + tc)];
  __syncthreads();
#pragma unroll
  for (int i = 0; i < 4; ++i)
    out[(size_t)(n0 + tr + i * 8) * K + (k0 + tc)] = f2bf(tile[tc][tr + i * 8]);
}

// ---------------- GEMM: C[M][N] = A[M][K](bf16) @ Bt[N][K](bf16)^T + bias ----------------
// 128x128 tile, BK=32, 4 waves (2x2), global_load_lds w16.
// T3-minimum 2-phase: double-buffered LDS, stage(t+1) issued BEFORE compute(t),
// ONE barrier per K-step (compiler emits vmcnt(0)+lgkmcnt(0) before s_barrier).
template <bool OUT_BF16>
__global__ __launch_bounds__(256) void gemm_bt(
    const u16* __restrict__ A, const u16* __restrict__ Bt,
    const float* __restrict__ bias, void* __restrict__ Cout,
    int M, int N, int K, int Mtiles, int Ntiles) {
  __shared__ char Al[2][128 * 32 * 2];
  __shared__ char Bl[2][128 * 32 * 2];

  const int nwg = Mtiles * Ntiles;           // must be divisible by 8
  int bid = (int)blockIdx.x;
  bid = (bid & 7) * (nwg >> 3) + (bid >> 3); // XCD-aware swizzle (bijective)
  const int mt = bid / Ntiles, nt = bid % Ntiles;
  const int m0 = mt * 128, n0 = nt * 128;

  const int tid = (int)threadIdx.x;
  const int lane = tid & 63;
  const int wv = tid >> 6;
  const int wm = wv & 1, wn = wv >> 1;
  const int lr = lane & 15, lg = lane >> 4;
  const int rsub = lane >> 2;  // row-within-chunk
  const int slot = lane & 3;   // 16B slot within 64B row

  // hoisted per-lane staging addresses (row clamped; stores are guarded)
  int ra = m0 + rsub;          // chunk row base added per-chunk below
  const int rb0 = n0 + rsub;

  auto stage = [&](int buf, int t) {
    const int k0 = t << 5;
#pragma unroll
    for (int c = 0; c < 2; ++c) {
      const int ci = c * 4 + wv;  // chunk 0..7, wave-uniform
      int rra = m0 + ci * 16 + rsub;
      if (rra >= M) rra = M - 1;
      gload_lds16(A + (size_t)rra * K + k0 + slot * 8, Al[buf] + ci * 1024);
      const int rrb = rb0 + ci * 16;  // N exact multiple of 128
      gload_lds16(Bt + (size_t)rrb * K + k0 + slot * 8, Bl[buf] + ci * 1024);
    }
  };
  (void)ra;

  f32x4 zero4 = {0.f, 0.f, 0.f, 0.f};
  f32x4 acc[4][4];
#pragma unroll
  for (int i = 0; i < 4; ++i)
#pragma unroll
    for (int j = 0; j < 4; ++j) acc[i][j] = zero4;

  const int nk = K >> 5;
  int cur = 0;
  stage(0, 0);
  __syncthreads();  // vmcnt(0): buf0 ready

  for (int t = 0; t < nk; ++t) {
    if (t + 1 < nk) stage(cur ^ 1, t + 1);  // async loads overlap compute below
    frag_t af[4], bf[4];
#pragma unroll
    for (int i = 0; i < 4; ++i) {
      af[i] = *(const frag_t*)(Al[cur] + (wm * 64 + i * 16 + lr) * 64 + lg * 16);
      bf[i] = *(const frag_t*)(Bl[cur] + (wn * 64 + i * 16 + lr) * 64 + lg * 16);
    }
#pragma unroll
    for (int i = 0; i < 4; ++i)
#pragma unroll
      for (int j = 0; j < 4; ++j)
        acc[i][j] = mfma_bf16(af[i], bf[j], acc[i][j]);
    __syncthreads();  // drains vmcnt(0): next buffer ready; this buffer consumed
    cur ^= 1;
  }

  // epilogue: C row = (lg*4+reg), col = lr within each 16x16 frag.
  // bf16 path: pack lane-pairs -> dword stores (avoid L2 RMW write amplification).
#pragma unroll
  for (int j = 0; j < 4; ++j) {
    const int col = n0 + wn * 64 + j * 16 + lr;
    const float bv = bias[col];
#pragma unroll
    for (int i = 0; i < 4; ++i) {
      const int rbase = m0 + wm * 64 + i * 16 + lg * 4;
#pragma unroll
      for (int r = 0; r < 4; ++r) {
        const int row = rbase + r;
        const float val = acc[i][j][r] + bv;
        if constexpr (OUT_BF16) {
          u32 me = f2bf(val);
          u32 other = __shfl_xor(me, 1);
          if ((lane & 1) == 0 && row < M) {
            *(u32*)((u16*)Cout + (size_t)row * N + col) = me | (other << 16);
          }
        } else {
          if (row < M) ((float*)Cout)[(size_t)row * N + col] = val;
        }
      }
    }
  }
}

// ---------------- attention: per (b, h, 64 q-rows) block, 4 waves x 16 q-rows ----------------
// Swapped QK^T: S^T tiles = mfma(K_frag, Q_frag) so softmax rows are 4-lane-local.
__global__ __launch_bounds__(256) void attn_kernel(
    const u16* __restrict__ Q, const u16* __restrict__ K,
    const u16* __restrict__ V, u16* __restrict__ O) {
  __shared__ u16 Kl[96][72];   // keys padded to 96
  __shared__ u16 Vt[64][104];  // V transposed: [dim][key], keys 77..95 zeroed

  const int bid = blockIdx.x;
  const int qt = bid & 63;
  const int h = (bid >> 6) & 15;
  const int b = bid >> 10;
  const int tid = threadIdx.x;

  // stage K (zero-pad keys >= 77): 96 keys x 8 x 16B slots = 768 = 3*256
#pragma unroll
  for (int it = 0; it < 3; ++it) {
    const int idx = tid + it * 256;
    const int key = idx >> 3, s = idx & 7;
    uint4 val{0u, 0u, 0u, 0u};
    if (key < 77)
      val = *(const uint4*)(K + ((size_t)(b * 77 + key)) * 1024 + h * 64 + s * 8);
    *(uint4*)(&Kl[key][s * 8]) = val;
  }
  // stage V transposed, vectorized global side: 77 keys x 8 uint4 slots = 616
#pragma unroll
  for (int it = 0; it < 3; ++it) {
    const int idx = tid + it * 256;
    if (idx < 616) {
      const int key = idx >> 3, s = idx & 7;
      const uint4 v4 =
          *(const uint4*)(V + ((size_t)(b * 77 + key)) * 1024 + h * 64 + s * 8);
      const u16* e = (const u16*)&v4;
#pragma unroll
      for (int j = 0; j < 8; ++j) Vt[s * 8 + j][key] = e[j];
    }
  }
  // zero keys 77..95 (read by PV B-frags, multiplied by zero P — must be finite)
#pragma unroll
  for (int it = 0; it < 5; ++it) {
    const int idx = tid + it * 256;
    if (idx < 1216) {  // 64 dims * 19 keys
      const int d = idx / 19, kk = 77 + idx % 19;
      Vt[d][kk] = 0;
    }
  }
  __syncthreads();

  const int lane = tid & 63;
  const int wv = tid >> 6;  // wave -> q rows [wv*16, wv*16+16)
  const int lr = lane & 15;
  const int lg = lane >> 4;

  // Q fragments straight from global (no LDS round-trip)
  const size_t qrow = (size_t)(b * 4096 + qt * 64 + wv * 16 + lr) * 1024 + h * 64;
  frag_t qf[2];
#pragma unroll
  for (int ks = 0; ks < 2; ++ks)
    qf[ks] = *(const frag_t*)(Q + qrow + ks * 32 + lg * 8);

  // S^T: 5 key-tiles x (K=64 -> 2 mfma)
  f32x4 zero4 = {0.f, 0.f, 0.f, 0.f};
  f32x4 sa[5] = {zero4, zero4, zero4, zero4, zero4};
#pragma unroll
  for (int ks = 0; ks < 2; ++ks) {
#pragma unroll
    for (int kt = 0; kt < 5; ++kt) {
      frag_t kf = *(const frag_t*)(&Kl[kt * 16 + lr][ks * 32 + lg * 8]);
      sa[kt] = mfma_bf16(kf, qf[ks], sa[kt]);
    }
  }

  // softmax: lane owns q-row lr; keys kt*16 + lg*4 + r; reduce over lanes ^16,^32
  float p[5][4];
  float mx = -3.0e38f;
#pragma unroll
  for (int kt = 0; kt < 5; ++kt)
#pragma unroll
    for (int r = 0; r < 4; ++r) {
      const int key = kt * 16 + lg * 4 + r;
      float s = sa[kt][r] * 0.125f;  // 1/sqrt(64)
      if (key >= 77) s = -3.0e38f;
      p[kt][r] = s;
      mx = fmaxf(mx, s);
    }
  mx = fmaxf(mx, __shfl_xor(mx, 16));
  mx = fmaxf(mx, __shfl_xor(mx, 32));
  float sum = 0.f;
#pragma unroll
  for (int kt = 0; kt < 5; ++kt)
#pragma unroll
    for (int r = 0; r < 4; ++r) {
      const float e = __expf(p[kt][r] - mx);
      p[kt][r] = e;
      sum += e;
    }
  sum += __shfl_xor(sum, 16);
  sum += __shfl_xor(sum, 32);
  const float rden = 1.0f / sum;
#pragma unroll
  for (int kt = 0; kt < 5; ++kt)
#pragma unroll
    for (int r = 0; r < 4; ++r) p[kt][r] *= rden;

  // pack P fragments: A-operand row = lr = q-row; kappa(l,j) = (2kb+j>>2)*16+lg*4+(j&3);
  // V B-fragment uses identical kappa -> sum over k is permutation-invariant.
  union FP { frag_t v; u16 e[8]; };
  frag_t pa[3];
#pragma unroll
  for (int kb = 0; kb < 3; ++kb) {
    FP f;
#pragma unroll
    for (int j = 0; j < 8; ++j) {
      const int kt = 2 * kb + (j >> 2);
      f.e[j] = (kt < 5) ? f2bf(p[kt][j & 3]) : (u16)0;
    }
    pa[kb] = f.v;
  }

  // O = P @ V : 4 dim-tiles x 3 K-blocks (96 keys)
  f32x4 oa[4] = {zero4, zero4, zero4, zero4};
#pragma unroll
  for (int nt = 0; nt < 4; ++nt) {
    const int d = nt * 16 + lr;
#pragma unroll
    for (int kb = 0; kb < 3; ++kb) {
      const int key0 = kb * 32 + lg * 4;
      FP vb;
      *(uint2*)(&vb.e[0]) = *(const uint2*)(&Vt[d][key0]);
      *(uint2*)(&vb.e[4]) = *(const uint2*)(&Vt[d][key0 + 16]);
      oa[nt] = mfma_bf16(pa[kb], vb.v, oa[nt]);
    }
  }

  // store: row=(lg*4+r)=q-row, col=lr=dim; pack lane pairs -> dword stores
#pragma unroll
  for (int nt = 0; nt < 4; ++nt)
#pragma unroll
    for (int r = 0; r < 4; ++r) {
      const int qr = wv * 16 + lg * 4 + r;
      u32 me = f2bf(oa[nt][r]);
      u32 other = __shfl_xor(me, 1);
      if ((lane & 1) == 0) {
        *(u32*)(O + ((size_t)(b * 4096 + qt * 64 + qr)) * 1024 + h * 64 +
                nt * 16 + lr) = me | (other << 16);
      }
    }
}

// ---------------- launch ----------------
extern "C" void kernel_launch(void* const* d_in, const int* in_sizes, int n_in,
                              void* d_out, int out_size, void* d_ws, size_t ws_size,
                              hipStream_t stream) {
  const float* x  = (const float*)d_in[0];
  const float* p  = (const float*)d_in[1];
  const float* Wq = (const float*)d_in[2];
  const float* bq = (const float*)d_in[3];
  const float* Wk = (const float*)d_in[4];
  const float* bk = (const float*)d_in[5];
  const float* Wv = (const float*)d_in[6];
  const float* bv = (const float*)d_in[7];
  const float* Ww = (const float*)d_in[8];
  const float* bw = (const float*)d_in[9];

  char* ws = (char*)d_ws;
  if (ws_size < 281034752ULL) return;  // loud failure if scratch too small

  u16* x_bf = (u16*)(ws + 0);          // 65536x1024 bf16; reused as attn_out after GEMM1
  u16* q_bf = (u16*)(ws + 134217728);  // 65536x1024
  u16* wq_t = (u16*)(ws + 268435456);  // [1024][1024]
  u16* ww_t = (u16*)(ws + 270532608);  // [1024][1024]
  u16* wk_t = (u16*)(ws + 272629760);  // [1024][512]
  u16* wv_t = (u16*)(ws + 273678336);  // [1024][512]
  u16* p_bf = (u16*)(ws + 274726912);  // 1232x512
  u16* k_bf = (u16*)(ws + 275988480);  // 1232x1024
  u16* v_bf = (u16*)(ws + 278511616);  // 1232x1024

  cast_f32_bf16<<<4096, 256, 0, stream>>>(x, x_bf, 8388608);   // 67.1M elems
  cast_f32_bf16<<<308, 256, 0, stream>>>(p, p_bf, 78848);      // 630784 elems
  transpose_cast<<<dim3(32, 32), 256, 0, stream>>>(Wq, wq_t, 1024, 1024);
  transpose_cast<<<dim3(32, 32), 256, 0, stream>>>(Ww, ww_t, 1024, 1024);
  transpose_cast<<<dim3(16, 32), 256, 0, stream>>>(Wk, wk_t, 512, 1024);
  transpose_cast<<<dim3(16, 32), 256, 0, stream>>>(Wv, wv_t, 512, 1024);

  // K/V projections: M=1232 (pad to 10 tiles), K=512, N=1024
  gemm_bt<true><<<80, 256, 0, stream>>>(p_bf, wk_t, bk, k_bf, 1232, 1024, 512, 10, 8);
  gemm_bt<true><<<80, 256, 0, stream>>>(p_bf, wv_t, bv, v_bf, 1232, 1024, 512, 10, 8);
  // Q projection: 65536x1024x1024
  gemm_bt<true><<<4096, 256, 0, stream>>>(x_bf, wq_t, bq, q_bf, 65536, 1024, 1024, 512, 8);
  // attention (writes attn_out into x_bf region — x is dead after GEMM1)
  attn_kernel<<<16384, 256, 0, stream>>>(q_bf, k_bf, v_bf, x_bf);
  // out projection -> fp32
  gemm_bt<false><<<4096, 256, 0, stream>>>(x_bf, ww_t, bw, d_out, 65536, 1024, 1024, 512, 8);
}

// Round 3
// 625.566 us; speedup vs baseline: 1.3212x; 1.1372x over previous
//
#include <hip/hip_runtime.h>
#include <cstdint>
#include <type_traits>

typedef uint16_t u16;
typedef uint32_t u32;
typedef __attribute__((ext_vector_type(4))) float f32x4;
typedef __attribute__((ext_vector_type(8))) __bf16 vbf8;
typedef __attribute__((ext_vector_type(8))) short vs8;

// ---- MFMA operand-type hedge: prefer v8bf16, fall back to v8i16 ----
template <typename T, typename = void>
struct CanMfma : std::false_type {};
template <typename T>
struct CanMfma<T, std::void_t<decltype(__builtin_amdgcn_mfma_f32_16x16x32_bf16(
    std::declval<T>(), std::declval<T>(), std::declval<f32x4>(), 0, 0, 0))>>
    : std::true_type {};
typedef std::conditional_t<CanMfma<vbf8>::value, vbf8, vs8> frag_t;

__device__ __forceinline__ f32x4 mfma_bf16(frag_t a, frag_t b, f32x4 c) {
  return __builtin_amdgcn_mfma_f32_16x16x32_bf16(a, b, c, 0, 0, 0);
}

__device__ __forceinline__ u16 f2bf(float f) {
  u32 u = __builtin_bit_cast(u32, f);
  u32 r = (u + 0x7FFFu + ((u >> 16) & 1u)) >> 16;
  return (u16)r;
}

__device__ __forceinline__ void gload_lds16(const void* g, void* l) {
  __builtin_amdgcn_global_load_lds(
      (const __attribute__((address_space(1))) void*)g,
      (__attribute__((address_space(3))) void*)l, 16, 0, 0);
}

// ---------------- cast fp32 -> bf16 ----------------
__global__ __launch_bounds__(256) void cast_f32_bf16(
    const float* __restrict__ in, u16* __restrict__ out, int n8) {
  int i = blockIdx.x * 256 + threadIdx.x;
  const int stride = gridDim.x * 256;
  for (; i < n8; i += stride) {
    const float4 a  = ((const float4*)in)[(size_t)i * 2];
    const float4 b2 = ((const float4*)in)[(size_t)i * 2 + 1];
    uint4 o;
    o.x = (u32)f2bf(a.x)  | ((u32)f2bf(a.y)  << 16);
    o.y = (u32)f2bf(a.z)  | ((u32)f2bf(a.w)  << 16);
    o.z = (u32)f2bf(b2.x) | ((u32)f2bf(b2.y) << 16);
    o.w = (u32)f2bf(b2.z) | ((u32)f2bf(b2.w) << 16);
    ((uint4*)out)[(size_t)i] = o;
  }
}

// ---------------- transpose + cast: in[K][N] f32 -> out[N][K] bf16 ----------------
__global__ __launch_bounds__(256) void transpose_cast(
    const float* __restrict__ in, u16* __restrict__ out, int K, int N) {
  __shared__ float tile[32][33];
  const int k0 = blockIdx.x * 32, n0 = blockIdx.y * 32;
  const int tr = threadIdx.x >> 5, tc = threadIdx.x & 31;
#pragma unroll
  for (int i = 0; i < 4; ++i)
    tile[tr + i * 8][tc] = in[(size_t)(k0 + tr + i * 8) * N + (n0 + tc)];
  __syncthreads();
#pragma unroll
  for (int i = 0; i < 4; ++i)
    out[(size_t)(n0 + tr + i * 8) * K + (k0 + tc)] = f2bf(tile[tc][tr + i * 8]);
}

// ---------------- small GEMM (128^2, 2-phase dbuf) for K/V projections ----------------
template <bool OUT_BF16>
__global__ __launch_bounds__(256) void gemm_bt(
    const u16* __restrict__ A, const u16* __restrict__ Bt,
    const float* __restrict__ bias, void* __restrict__ Cout,
    int M, int N, int K, int Mtiles, int Ntiles) {
  __shared__ char Al[2][128 * 32 * 2];
  __shared__ char Bl[2][128 * 32 * 2];

  const int nwg = Mtiles * Ntiles;
  int bid = (int)blockIdx.x;
  bid = (bid & 7) * (nwg >> 3) + (bid >> 3);
  const int mt = bid / Ntiles, nt = bid % Ntiles;
  const int m0 = mt * 128, n0 = nt * 128;

  const int tid = (int)threadIdx.x;
  const int lane = tid & 63;
  const int wv = tid >> 6;
  const int wm = wv & 1, wn = wv >> 1;
  const int lr = lane & 15, lg = lane >> 4;
  const int rsub = lane >> 2;
  const int slot = lane & 3;
  const int rb0 = n0 + rsub;

  auto stage = [&](int buf, int t) {
    const int k0 = t << 5;
#pragma unroll
    for (int c = 0; c < 2; ++c) {
      const int ci = c * 4 + wv;
      int rra = m0 + ci * 16 + rsub;
      if (rra >= M) rra = M - 1;
      gload_lds16(A + (size_t)rra * K + k0 + slot * 8, Al[buf] + ci * 1024);
      const int rrb = rb0 + ci * 16;
      gload_lds16(Bt + (size_t)rrb * K + k0 + slot * 8, Bl[buf] + ci * 1024);
    }
  };

  f32x4 zero4 = {0.f, 0.f, 0.f, 0.f};
  f32x4 acc[4][4];
#pragma unroll
  for (int i = 0; i < 4; ++i)
#pragma unroll
    for (int j = 0; j < 4; ++j) acc[i][j] = zero4;

  const int nk = K >> 5;
  int cur = 0;
  stage(0, 0);
  __syncthreads();

  for (int t = 0; t < nk; ++t) {
    if (t + 1 < nk) stage(cur ^ 1, t + 1);
    frag_t af[4], bf[4];
#pragma unroll
    for (int i = 0; i < 4; ++i) {
      af[i] = *(const frag_t*)(Al[cur] + (wm * 64 + i * 16 + lr) * 64 + lg * 16);
      bf[i] = *(const frag_t*)(Bl[cur] + (wn * 64 + i * 16 + lr) * 64 + lg * 16);
    }
#pragma unroll
    for (int i = 0; i < 4; ++i)
#pragma unroll
      for (int j = 0; j < 4; ++j)
        acc[i][j] = mfma_bf16(af[i], bf[j], acc[i][j]);
    __syncthreads();
    cur ^= 1;
  }

#pragma unroll
  for (int j = 0; j < 4; ++j) {
    const int col = n0 + wn * 64 + j * 16 + lr;
    const float bv = bias[col];
#pragma unroll
    for (int i = 0; i < 4; ++i) {
      const int rbase = m0 + wm * 64 + i * 16 + lg * 4;
#pragma unroll
      for (int r = 0; r < 4; ++r) {
        const int row = rbase + r;
        const float val = acc[i][j][r] + bv;
        if constexpr (OUT_BF16) {
          u32 me = f2bf(val);
          u32 other = __shfl_xor(me, 1);
          if ((lane & 1) == 0 && row < M) {
            *(u32*)((u16*)Cout + (size_t)row * N + col) = me | (other << 16);
          }
        } else {
          if (row < M) ((float*)Cout)[(size_t)row * N + col] = val;
        }
      }
    }
  }
}

// ---------------- big GEMM: 256^2 tile, BK=64, 8-phase counted-vmcnt pipeline ----------
// T1 (XCD swizzle) + T2 (src-preswizzled LDS, 2-way free) + T3/T4 (counted vmcnt(4),
// never 0 mid-loop) + T5 (setprio around MFMA). M,N multiples of 256; K mult of 128.
template <bool OUT_BF16>
__global__ __launch_bounds__(512) void gemm256(
    const u16* __restrict__ A, const u16* __restrict__ Bt,
    const float* __restrict__ bias, void* __restrict__ Cout,
    int M, int N, int K) {
  __shared__ u16 Al[2][256 * 64];
  __shared__ u16 Bl[2][256 * 64];

  const int Ntiles = N >> 8;
  const int nwg = (M >> 8) * Ntiles;
  int bid = (int)blockIdx.x;
  bid = (bid & 7) * (nwg >> 3) + (bid >> 3);  // bijective: nwg % 8 == 0
  const int mt = bid / Ntiles, ntl = bid % Ntiles;
  const int m0 = mt << 8, n0 = ntl << 8;

  const int tid = (int)threadIdx.x;
  const int lane = tid & 63;
  const int wid = tid >> 6;
  const int wm = wid >> 2, wn = wid & 3;  // 2 x 4 wave grid
  const int lr = lane & 15, lg = lane >> 4;
  const int lrx = lr & 7;

  // staging: wave stages chunks (wid*2, wid*2+1); 8 rows x 128B each.
  const int chunk = wid * 2;
  const int srow = lane >> 3;
  const int sslot = (lane & 7) ^ srow;  // pre-swizzled source slot (rule 21)
  const u16* Abase = A + (size_t)(m0 + chunk * 8 + srow) * K + sslot * 8;
  const u16* Bbase = Bt + (size_t)(n0 + chunk * 8 + srow) * K + sslot * 8;
  const int ldsChunkByte = (chunk * 8) * 128;

  auto stA = [&](u16* dst, int h, int t) {
    const u16* g = Abase + (size_t)(h << 7) * K + (t << 6);
    char* l = (char*)dst + (h << 14) + ldsChunkByte;
    gload_lds16(g, l);
    gload_lds16(g + ((size_t)K << 3), l + 1024);
  };
  auto stB = [&](u16* dst, int h, int t) {
    const u16* g = Bbase + (size_t)(h << 7) * K + (t << 6);
    char* l = (char*)dst + (h << 14) + ldsChunkByte;
    gload_lds16(g, l);
    gload_lds16(g + ((size_t)K << 3), l + 1024);
  };

  // swizzled ds_read of one 16B frag: row in [0,256), logical slot = ks*4+lg
  auto ldsF = [&](const u16* base, int row, int ks) -> frag_t {
    return *(const frag_t*)(base + (size_t)row * 64 + ((((ks) << 2) + lg) ^ lrx) * 8);
  };

  f32x4 zero4 = {0.f, 0.f, 0.f, 0.f};
  f32x4 acc[8][4];
#pragma unroll
  for (int i = 0; i < 8; ++i)
#pragma unroll
    for (int j = 0; j < 4; ++j) acc[i][j] = zero4;

  const int nt = K >> 6;  // K-tiles; require even, >= 4
  const int ar0 = wm * 128 + lr;
  const int br0 = wn * 64 + lr;

  // Serpentine phases per tile: P0:A0xB0  P1:A0xB1  P2:A1xB1  P3:A1xB0.
  // Stage stream: P0:A0(t+1) P1:A1(t+1) P2:B0(t+2) P3:B1(t+2). Boundary vmcnt(4).
  auto tileStep = [&](const u16* al, const u16* bl, u16* adst, u16* bdst,
                      int tA, int tB, bool onA, bool onB, int vm) {
    frag_t a[4][2], b0[2][2], b1[2][2];
    // ---- P0 ----
#pragma unroll
    for (int i = 0; i < 4; ++i) {
      a[i][0] = ldsF(al, ar0 + i * 16, 0);
      a[i][1] = ldsF(al, ar0 + i * 16, 1);
    }
#pragma unroll
    for (int j = 0; j < 2; ++j) {
      b0[j][0] = ldsF(bl, br0 + j * 16, 0);
      b0[j][1] = ldsF(bl, br0 + j * 16, 1);
    }
    if (onA) stA(adst, 0, tA);
    __builtin_amdgcn_s_barrier();
    __builtin_amdgcn_s_setprio(1);
#pragma unroll
    for (int i = 0; i < 4; ++i)
#pragma unroll
      for (int j = 0; j < 2; ++j) {
        acc[i][j] = mfma_bf16(a[i][0], b0[j][0], acc[i][j]);
        acc[i][j] = mfma_bf16(a[i][1], b0[j][1], acc[i][j]);
      }
    __builtin_amdgcn_s_setprio(0);
    __builtin_amdgcn_s_barrier();
    // ---- P1 ----
#pragma unroll
    for (int j = 0; j < 2; ++j) {
      b1[j][0] = ldsF(bl, br0 + 32 + j * 16, 0);
      b1[j][1] = ldsF(bl, br0 + 32 + j * 16, 1);
    }
    if (onA) stA(adst, 1, tA);
    __builtin_amdgcn_s_barrier();
    __builtin_amdgcn_s_setprio(1);
#pragma unroll
    for (int i = 0; i < 4; ++i)
#pragma unroll
      for (int j = 0; j < 2; ++j) {
        acc[i][2 + j] = mfma_bf16(a[i][0], b1[j][0], acc[i][2 + j]);
        acc[i][2 + j] = mfma_bf16(a[i][1], b1[j][1], acc[i][2 + j]);
      }
    __builtin_amdgcn_s_setprio(0);
    __builtin_amdgcn_s_barrier();
    // ---- P2 ----
#pragma unroll
    for (int i = 0; i < 4; ++i) {
      a[i][0] = ldsF(al, ar0 + 64 + i * 16, 0);
      a[i][1] = ldsF(al, ar0 + 64 + i * 16, 1);
    }
    if (onB) stB(bdst, 0, tB);
    __builtin_amdgcn_s_barrier();
    __builtin_amdgcn_s_setprio(1);
#pragma unroll
    for (int i = 0; i < 4; ++i)
#pragma unroll
      for (int j = 0; j < 2; ++j) {
        acc[4 + i][2 + j] = mfma_bf16(a[i][0], b1[j][0], acc[4 + i][2 + j]);
        acc[4 + i][2 + j] = mfma_bf16(a[i][1], b1[j][1], acc[4 + i][2 + j]);
      }
    __builtin_amdgcn_s_setprio(0);
    __builtin_amdgcn_s_barrier();
    // ---- P3 ----
    if (onB) stB(bdst, 1, tB);
    __builtin_amdgcn_s_barrier();
    __builtin_amdgcn_s_setprio(1);
#pragma unroll
    for (int i = 0; i < 4; ++i)
#pragma unroll
      for (int j = 0; j < 2; ++j) {
        acc[4 + i][j] = mfma_bf16(a[i][0], b0[j][0], acc[4 + i][j]);
        acc[4 + i][j] = mfma_bf16(a[i][1], b0[j][1], acc[4 + i][j]);
      }
    __builtin_amdgcn_s_setprio(0);
    // boundary: counted drain (never 0 mid-loop), then release barrier
    if (vm == 4)
      asm volatile("s_waitcnt vmcnt(4)" ::: "memory");
    else if (vm == 0)
      asm volatile("s_waitcnt vmcnt(0)" ::: "memory");
    __builtin_amdgcn_s_barrier();
  };

  // prologue: tile0 (A0,A1,B0,B1) + B halves of tile1; drain to 4 (B(1) in flight)
  stA(&Al[0][0], 0, 0);
  stA(&Al[0][0], 1, 0);
  stB(&Bl[0][0], 0, 0);
  stB(&Bl[0][0], 1, 0);
  stB(&Bl[1][0], 0, 1);
  stB(&Bl[1][0], 1, 1);
  asm volatile("s_waitcnt vmcnt(4)" ::: "memory");
  __builtin_amdgcn_s_barrier();

  for (int t = 0; t + 2 < nt; t += 2) {
    tileStep(&Al[0][0], &Bl[0][0], &Al[1][0], &Bl[0][0], t + 1, t + 2, true, true, 4);
    tileStep(&Al[1][0], &Bl[1][0], &Al[0][0], &Bl[1][0], t + 2, t + 3,
             true, t + 3 < nt, (t + 3 < nt) ? 4 : 0);
  }
  // peeled last two tiles (nt even): tile nt-2 on buf0, nt-1 on buf1
  tileStep(&Al[0][0], &Bl[0][0], &Al[1][0], &Bl[0][0], nt - 1, nt, true, false, 0);
  tileStep(&Al[1][0], &Bl[1][0], &Al[0][0], &Bl[1][0], nt, nt, false, false, -1);

  // epilogue: row = m0+wm*128+(ai>>2)*64+(ai&3)*16+lg*4+rr ; col = n0+wn*64+(bj>>1)*32+(bj&1)*16+lr
#pragma unroll
  for (int bj = 0; bj < 4; ++bj) {
    const int col = n0 + wn * 64 + (bj >> 1) * 32 + (bj & 1) * 16 + lr;
    const float bv = bias[col];
#pragma unroll
    for (int ai = 0; ai < 8; ++ai) {
      const int rbase = m0 + wm * 128 + (ai >> 2) * 64 + (ai & 3) * 16 + lg * 4;
#pragma unroll
      for (int rr = 0; rr < 4; ++rr) {
        const float val = acc[ai][bj][rr] + bv;
        if constexpr (OUT_BF16) {
          u32 me = f2bf(val);
          u32 other = __shfl_xor(me, 1);
          if ((lane & 1) == 0) {
            *(u32*)((u16*)Cout + (size_t)(rbase + rr) * N + col) = me | (other << 16);
          }
        } else {
          ((float*)Cout)[(size_t)(rbase + rr) * N + col] = val;
        }
      }
    }
  }
}

// ---------------- attention (unchanged, passing) ----------------
__global__ __launch_bounds__(256) void attn_kernel(
    const u16* __restrict__ Q, const u16* __restrict__ K,
    const u16* __restrict__ V, u16* __restrict__ O) {
  __shared__ u16 Kl[96][72];
  __shared__ u16 Vt[64][104];

  const int bid = blockIdx.x;
  const int qt = bid & 63;
  const int h = (bid >> 6) & 15;
  const int b = bid >> 10;
  const int tid = threadIdx.x;

#pragma unroll
  for (int it = 0; it < 3; ++it) {
    const int idx = tid + it * 256;
    const int key = idx >> 3, s = idx & 7;
    uint4 val{0u, 0u, 0u, 0u};
    if (key < 77)
      val = *(const uint4*)(K + ((size_t)(b * 77 + key)) * 1024 + h * 64 + s * 8);
    *(uint4*)(&Kl[key][s * 8]) = val;
  }
#pragma unroll
  for (int it = 0; it < 3; ++it) {
    const int idx = tid + it * 256;
    if (idx < 616) {
      const int key = idx >> 3, s = idx & 7;
      const uint4 v4 =
          *(const uint4*)(V + ((size_t)(b * 77 + key)) * 1024 + h * 64 + s * 8);
      const u16* e = (const u16*)&v4;
#pragma unroll
      for (int j = 0; j < 8; ++j) Vt[s * 8 + j][key] = e[j];
    }
  }
#pragma unroll
  for (int it = 0; it < 5; ++it) {
    const int idx = tid + it * 256;
    if (idx < 1216) {
      const int d = idx / 19, kk = 77 + idx % 19;
      Vt[d][kk] = 0;
    }
  }
  __syncthreads();

  const int lane = tid & 63;
  const int wv = tid >> 6;
  const int lr = lane & 15;
  const int lg = lane >> 4;

  const size_t qrow = (size_t)(b * 4096 + qt * 64 + wv * 16 + lr) * 1024 + h * 64;
  frag_t qf[2];
#pragma unroll
  for (int ks = 0; ks < 2; ++ks)
    qf[ks] = *(const frag_t*)(Q + qrow + ks * 32 + lg * 8);

  f32x4 zero4 = {0.f, 0.f, 0.f, 0.f};
  f32x4 sa[5] = {zero4, zero4, zero4, zero4, zero4};
#pragma unroll
  for (int ks = 0; ks < 2; ++ks) {
#pragma unroll
    for (int kt = 0; kt < 5; ++kt) {
      frag_t kf = *(const frag_t*)(&Kl[kt * 16 + lr][ks * 32 + lg * 8]);
      sa[kt] = mfma_bf16(kf, qf[ks], sa[kt]);
    }
  }

  float p[5][4];
  float mx = -3.0e38f;
#pragma unroll
  for (int kt = 0; kt < 5; ++kt)
#pragma unroll
    for (int r = 0; r < 4; ++r) {
      const int key = kt * 16 + lg * 4 + r;
      float s = sa[kt][r] * 0.125f;
      if (key >= 77) s = -3.0e38f;
      p[kt][r] = s;
      mx = fmaxf(mx, s);
    }
  mx = fmaxf(mx, __shfl_xor(mx, 16));
  mx = fmaxf(mx, __shfl_xor(mx, 32));
  float sum = 0.f;
#pragma unroll
  for (int kt = 0; kt < 5; ++kt)
#pragma unroll
    for (int r = 0; r < 4; ++r) {
      const float e = __expf(p[kt][r] - mx);
      p[kt][r] = e;
      sum += e;
    }
  sum += __shfl_xor(sum, 16);
  sum += __shfl_xor(sum, 32);
  const float rden = 1.0f / sum;
#pragma unroll
  for (int kt = 0; kt < 5; ++kt)
#pragma unroll
    for (int r = 0; r < 4; ++r) p[kt][r] *= rden;

  union FP { frag_t v; u16 e[8]; };
  frag_t pa[3];
#pragma unroll
  for (int kb = 0; kb < 3; ++kb) {
    FP f;
#pragma unroll
    for (int j = 0; j < 8; ++j) {
      const int kt = 2 * kb + (j >> 2);
      f.e[j] = (kt < 5) ? f2bf(p[kt][j & 3]) : (u16)0;
    }
    pa[kb] = f.v;
  }

  f32x4 oa[4] = {zero4, zero4, zero4, zero4};
#pragma unroll
  for (int nt = 0; nt < 4; ++nt) {
    const int d = nt * 16 + lr;
#pragma unroll
    for (int kb = 0; kb < 3; ++kb) {
      const int key0 = kb * 32 + lg * 4;
      FP vb;
      *(uint2*)(&vb.e[0]) = *(const uint2*)(&Vt[d][key0]);
      *(uint2*)(&vb.e[4]) = *(const uint2*)(&Vt[d][key0 + 16]);
      oa[nt] = mfma_bf16(pa[kb], vb.v, oa[nt]);
    }
  }

#pragma unroll
  for (int nt = 0; nt < 4; ++nt)
#pragma unroll
    for (int r = 0; r < 4; ++r) {
      const int qr = wv * 16 + lg * 4 + r;
      u32 me = f2bf(oa[nt][r]);
      u32 other = __shfl_xor(me, 1);
      if ((lane & 1) == 0) {
        *(u32*)(O + ((size_t)(b * 4096 + qt * 64 + qr)) * 1024 + h * 64 +
                nt * 16 + lr) = me | (other << 16);
      }
    }
}

// ---------------- launch ----------------
extern "C" void kernel_launch(void* const* d_in, const int* in_sizes, int n_in,
                              void* d_out, int out_size, void* d_ws, size_t ws_size,
                              hipStream_t stream) {
  const float* x  = (const float*)d_in[0];
  const float* p  = (const float*)d_in[1];
  const float* Wq = (const float*)d_in[2];
  const float* bq = (const float*)d_in[3];
  const float* Wk = (const float*)d_in[4];
  const float* bk = (const float*)d_in[5];
  const float* Wv = (const float*)d_in[6];
  const float* bv = (const float*)d_in[7];
  const float* Ww = (const float*)d_in[8];
  const float* bw = (const float*)d_in[9];

  char* ws = (char*)d_ws;
  if (ws_size < 281034752ULL) return;

  u16* x_bf = (u16*)(ws + 0);          // 65536x1024 bf16; reused as attn_out
  u16* q_bf = (u16*)(ws + 134217728);  // 65536x1024
  u16* wq_t = (u16*)(ws + 268435456);  // [1024][1024]
  u16* ww_t = (u16*)(ws + 270532608);  // [1024][1024]
  u16* wk_t = (u16*)(ws + 272629760);  // [1024][512]
  u16* wv_t = (u16*)(ws + 273678336);  // [1024][512]
  u16* p_bf = (u16*)(ws + 274726912);  // 1232x512
  u16* k_bf = (u16*)(ws + 275988480);  // 1232x1024
  u16* v_bf = (u16*)(ws + 278511616);  // 1232x1024

  cast_f32_bf16<<<4096, 256, 0, stream>>>(x, x_bf, 8388608);
  cast_f32_bf16<<<308, 256, 0, stream>>>(p, p_bf, 78848);
  transpose_cast<<<dim3(32, 32), 256, 0, stream>>>(Wq, wq_t, 1024, 1024);
  transpose_cast<<<dim3(32, 32), 256, 0, stream>>>(Ww, ww_t, 1024, 1024);
  transpose_cast<<<dim3(16, 32), 256, 0, stream>>>(Wk, wk_t, 512, 1024);
  transpose_cast<<<dim3(16, 32), 256, 0, stream>>>(Wv, wv_t, 512, 1024);

  // K/V projections (small): 2-phase 128^2 kernel
  gemm_bt<true><<<80, 256, 0, stream>>>(p_bf, wk_t, bk, k_bf, 1232, 1024, 512, 10, 8);
  gemm_bt<true><<<80, 256, 0, stream>>>(p_bf, wv_t, bv, v_bf, 1232, 1024, 512, 10, 8);
  // Q projection: 256^2 8-phase kernel (M=65536, N=1024, K=1024 -> 1024 blocks)
  gemm256<true><<<1024, 512, 0, stream>>>(x_bf, wq_t, bq, q_bf, 65536, 1024, 1024);
  // attention
  attn_kernel<<<16384, 256, 0, stream>>>(q_bf, k_bf, v_bf, x_bf);
  // out projection -> fp32
  gemm256<false><<<1024, 512, 0, stream>>>(x_bf, ww_t, bw, d_out, 65536, 1024, 1024);
}